// Round 21
// baseline (234.039 us; speedup 1.0000x reference)
//
#include <hip/hip_runtime.h>
#include <cstdint>

typedef __attribute__((ext_vector_type(8))) short short8;
typedef __attribute__((ext_vector_type(4))) float f32x4;
typedef const __attribute__((address_space(1))) uint32_t gu32;
typedef __attribute__((address_space(3))) uint32_t lu32;

#define WLDS 17536   // per-wave LDS: 16KB (ph2 2x8KB; ph1 ring = first 8KB) + 8*36 floats S

__device__ __forceinline__ unsigned short bf16_rne(float f) {
    unsigned u = __float_as_uint(f);
    u += 0x7FFFu + ((u >> 16) & 1u);
    return (unsigned short)(u >> 16);
}

// W fragment table for mfma_f32_16x16x32_bf16 B-operand (R15-verified):
// ushort idx = ks*2048 + nh*1024 + hl*512 + lane*8 + b;  Wt[e][k], e=jp*32+m
__global__ __launch_bounds__(1024) void wtab_kernel(const float* __restrict__ W,
                                                    unsigned short* __restrict__ tab) {
    int el = blockIdx.x * 1024 + threadIdx.x;   // 65536 elements
    int b    = el & 7;
    int lane = (el >> 3) & 63;
    int nh   = (el >> 9) & 1;
    int ks   = el >> 10;
    int e = ks * 32 + (lane >> 4) * 8 + b;
    int k = nh * 16 + (lane & 15);
    int jp = e >> 5, m = e & 31;
    float w = W[jp * 1024 + k * 32 + m];
    unsigned short hi = bf16_rne(w);
    float fh = __uint_as_float((unsigned)hi << 16);
    unsigned short lo = bf16_rne(w - fh);
    tab[(((ks * 2 + nh) * 2 + 0) * 64 + lane) * 8 + b] = hi;
    tab[(((ks * 2 + nh) * 2 + 1) * 64 + lane) * 8 + b] = lo;
}

__device__ __forceinline__ void split8(const float4& a, const float4& b,
                                       short8& hi, short8& lo) {
    float f[8] = {a.x, a.y, a.z, a.w, b.x, b.y, b.z, b.w};
    #pragma unroll
    for (int u = 0; u < 8; ++u) {
        unsigned short h = bf16_rne(f[u]);
        hi[u] = (short)h;
        float fh = __uint_as_float((unsigned)h << 16);
        lo[u] = (short)bf16_rne(f[u] - fh);
    }
}

// 256 threads = 4 fully independent waves (ZERO barriers). Wave owns 8 batches:
// the smaller tile keeps the chip-wide ph1->ph2 re-read window (~128 MB) inside
// the 256 MB L3, so phase-2 restreams from cache instead of HBM.
// MFMA M-rows 8..15 read duplicate rows (row = l&7): D rows 8..15 are dupes, ignored.
// ph1: 4x2KB chunk ring, DEPTH-3 prefetch (cover ~2.5 iters); ph2: 2x8KB row ring.
// All waits hand-counted vmcnt; tab loads counted, never drained.
__global__ __launch_bounds__(256) void ipf_kernel(const float* __restrict__ x,
                                                  const unsigned short* __restrict__ tab,
                                                  float* __restrict__ out) {
    extern __shared__ char smem[];
    const int t = threadIdx.x;
    const int w = t >> 6, l = t & 63;
    char* ring = smem + w * WLDS;                 // ph1: first 8KB (4x2KB); ph2: 16KB (2x8KB)
    float* Sl = (float*)(ring + 16384);           // 8 x 36 floats
    const long long b0 = ((long long)blockIdx.x * 4 + w) * 8;
    const char* gxt = (const char*)(x + b0 * 2048);   // 8 rows x 8 KB

    // ph1 stage chunk c (cols [c*256B, +256B) of 8 rows = 2KB): 2 DMA instrs.
    // LDS[chunk][row][p*16] = x[row][c*256 + (p*16 ^ (row&7)*16)]
    auto STAGE1 = [&](int c) {
        char* ld = ring + (c & 3) * 2048;
        #pragma unroll
        for (int u = 0; u < 2; ++u) {
            const int row = u * 4 + (l >> 4);
            const char* gs = gxt + (size_t)row * 8192 + c * 256
                           + (((l & 15) * 16) ^ ((row & 7) * 16));
            __builtin_amdgcn_global_load_lds((gu32*)gs, (lu32*)(ld + u * 1024), 16, 0, 0);
        }
    };
    // ph2 stage row r (8 KB linear): 8 DMA instrs.
    auto STAGE2 = [&](int r) {
        const char* gs = gxt + (size_t)r * 8192;
        char* ld = ring + (r & 1) * 8192;
        #pragma unroll
        for (int u = 0; u < 8; ++u)
            __builtin_amdgcn_global_load_lds((gu32*)(gs + u * 1024 + l * 16),
                                             (lu32*)(ld + u * 1024), 16, 0, 0);
    };

    f32x4 c0 = {0.f, 0.f, 0.f, 0.f};
    f32x4 c1 = {0.f, 0.f, 0.f, 0.f};

    STAGE1(0);
    STAGE1(1);
    STAGE1(2);

    // ---- phase 1: 32 chunk-iters, rhythm [wait][tab x8 + compute][stage x2] ----
    const int row = l & 7;                        // rows 8..15 duplicate 0..7 (D dupes)
    const int key = row * 16;
    #pragma unroll 1
    for (int c = 0; c < 32; ++c) {
        // queue walk (stage=2 instrs, tab=8/iter, depth-3):
        // c=0: [s0,s1,s2] -> 4 newer than s0. c=1: s2(2)+tab0(8)+s3(2)=12.
        // 2<=c<=29: tab(c-2,c-1)=16 + s(c+1),s(c+2)=4 -> 20. c=30: 18. c=31: 16.
        if (c == 0)       asm volatile("s_waitcnt vmcnt(4)" ::: "memory");
        else if (c == 1)  asm volatile("s_waitcnt vmcnt(12)" ::: "memory");
        else if (c < 30)  asm volatile("s_waitcnt vmcnt(20)" ::: "memory");
        else              asm volatile("s_waitcnt vmcnt(16)" ::: "memory");
        __builtin_amdgcn_sched_barrier(0);

        const char* cb = ring + (c & 3) * 2048 + row * 256;
        #pragma unroll
        for (int ksl = 0; ksl < 2; ++ksl) {
            const int p = (l >> 4) * 2 + ksl * 8;
            const float4 xa  = *(const float4*)(cb + ((p * 16) ^ key));
            const float4 xb2 = *(const float4*)(cb + (((p + 1) * 16) ^ key));
            const int ksg = c * 2 + ksl;
            const short8* tp = (const short8*)(tab + (size_t)ksg * 2048);
            const short8 wh0 = tp[l];
            const short8 wl0 = tp[64 + l];
            const short8 wh1 = tp[128 + l];
            const short8 wl1 = tp[192 + l];
            short8 xhi, xlo;
            split8(xa, xb2, xhi, xlo);
            c0 = __builtin_amdgcn_mfma_f32_16x16x32_bf16(xhi, wh0, c0, 0, 0, 0);
            c1 = __builtin_amdgcn_mfma_f32_16x16x32_bf16(xhi, wh1, c1, 0, 0, 0);
            c0 = __builtin_amdgcn_mfma_f32_16x16x32_bf16(xhi, wl0, c0, 0, 0, 0);
            c1 = __builtin_amdgcn_mfma_f32_16x16x32_bf16(xhi, wl1, c1, 0, 0, 0);
            c0 = __builtin_amdgcn_mfma_f32_16x16x32_bf16(xlo, wh0, c0, 0, 0, 0);
            c1 = __builtin_amdgcn_mfma_f32_16x16x32_bf16(xlo, wh1, c1, 0, 0, 0);
        }
        __builtin_amdgcn_sched_barrier(0);
        if (c + 3 < 32) STAGE1(c + 3);
    }

    // ---- S -> LDS: D rows 0..7 live in lanes l<32 (m89: row=(l>>4)*4+rr, col=l&15) ----
    if (l < 32) {
        #pragma unroll
        for (int rr = 0; rr < 4; ++rr) {
            Sl[((l >> 4) * 4 + rr) * 36 + (l & 15)]      = c0[rr];
            Sl[((l >> 4) * 4 + rr) * 36 + 16 + (l & 15)] = c1[rr];
        }
    }
    asm volatile("s_waitcnt lgkmcnt(0)" ::: "memory");   // S visible; ph1 ds ops retired
    __builtin_amdgcn_sched_barrier(0);

    STAGE2(0);
    STAGE2(1);

    // ---- phase 2: 8 row-iters (L3-hot restream), rhythm [wait][dot+store][stage x8] ----
    #pragma unroll 1
    for (int r = 0; r < 8; ++r) {
        // r=0: newer than stage2(0) = stage2(1) -> 8 (also drains leftover ph1 tabs).
        // 1<=r<=6: [stage(r+1)8, store(r-1)1] -> 9. r=7: store(6) -> 1.
        if (r == 0)      asm volatile("s_waitcnt vmcnt(8)" ::: "memory");
        else if (r < 7)  asm volatile("s_waitcnt vmcnt(9)" ::: "memory");
        else             asm volatile("s_waitcnt vmcnt(1)" ::: "memory");
        __builtin_amdgcn_sched_barrier(0);

        const char* rb = ring + (r & 1) * 8192;
        const float* sp = Sl + r * 36;
        float s = 0.0f;
        #pragma unroll
        for (int q = 0; q < 8; ++q) {
            const int p = (q + l) & 7;                    // rotated slot: uniform bank use
            const float4 xv = *(const float4*)(rb + l * 128 + p * 16);
            const float4 sv = *(const float4*)(sp + p * 4);
            s += xv.x * sv.x + xv.y * sv.y + xv.z * sv.z + xv.w * sv.w;
        }
        const float e2 = __expf(2.0f * s);                // tanh = 1 - 2/(e^{2s}+1)
        out[(b0 + r) * 64 + l] = 1.0f - 2.0f / (e2 + 1.0f);
        __builtin_amdgcn_sched_barrier(0);
        if (r + 2 < 8) STAGE2(r + 2);
    }
}

extern "C" void kernel_launch(void* const* d_in, const int* in_sizes, int n_in,
                              void* d_out, int out_size, void* d_ws, size_t ws_size,
                              hipStream_t stream) {
    const float* x = (const float*)d_in[0];          // [65536,64,32] fp32
    const float* W = (const float*)d_in[1];          // [64,32,32] fp32
    float* out = (float*)d_out;                      // [65536,64] fp32
    unsigned short* tab = (unsigned short*)d_ws;     // 131072 ushorts = 256 KB

    const size_t smem_bytes = 4 * WLDS;              // 70144 B -> 2 blocks/CU
    hipFuncSetAttribute((const void*)ipf_kernel,
                        hipFuncAttributeMaxDynamicSharedMemorySize, (int)smem_bytes);

    wtab_kernel<<<64, 1024, 0, stream>>>(W, tab);
    ipf_kernel<<<2048, 256, smem_bytes, stream>>>(x, tab, out);
}